// Round 7
// baseline (2562.347 us; speedup 1.0000x reference)
//
#include <hip/hip_runtime.h>

#define NB 8
#define CAP 128
#define NFEAT 704
#define MSLICE 8            // node slices per (batch,k) in moments
#define PSLICE (MSLICE * 4) // partial slots = slices * subs

using vf4 = __attribute__((ext_vector_type(4))) float;

// ---------------- setup kernels ----------------

__global__ void count_edges(const int* __restrict__ ei, int E, int* __restrict__ cnt) {
    int e = blockIdx.x * blockDim.x + threadIdx.x;
    if (e < E) atomicAdd(&cnt[ei[E + e]], 1);
}

__global__ void compute_dinv(const int* __restrict__ cnt, float* __restrict__ dinv, int n) {
    int v = blockIdx.x * blockDim.x + threadIdx.x;
    if (v < n) dinv[v] = rsqrtf((float)(cnt[v] + 1));  // +1 self-loop; always > 0
}

__global__ void fill_edges(const int* __restrict__ ei, int E, const float* __restrict__ dinv,
                           int* __restrict__ cursor, int2* __restrict__ pairs) {
    int e = blockIdx.x * blockDim.x + threadIdx.x;
    if (e < E) {
        int r = ei[e], c = ei[E + e];
        int pos = atomicAdd(&cursor[c], 1);
        if (pos < CAP) {
            float w = dinv[r] * dinv[c];
            pairs[(size_t)c * CAP + pos] = make_int2(r, __float_as_int(w));
        }
    }
}

// pad each node's edge list to a multiple of 16 with zero-weight edges
__global__ void pad_edges(const int* __restrict__ cnt, int2* __restrict__ pairs, int n) {
    int v = blockIdx.x * blockDim.x + threadIdx.x;
    if (v >= n) return;
    int c = min(cnt[v], CAP);
    int c16 = (c + 15) & ~15;
    for (int j = c; j < c16; ++j) pairs[(size_t)v * CAP + j] = make_int2(0, 0);
}

// batch is SORTED: boundaries, no atomics
__global__ void batch_bounds(const int* __restrict__ batch, int n, int* __restrict__ boff) {
    int i = blockIdx.x * blockDim.x + threadIdx.x;
    if (i >= n) return;
    int b = batch[i];
    int pb = (i == 0) ? -1 : batch[i - 1];
    for (int k = pb + 1; k <= b; ++k) boff[k] = i;
    if (i == n - 1) {
        for (int k = b + 1; k <= NB; ++k) boff[k] = n;
    }
}

// ---------------- cascade (16-channel units, one wave per node-step) ----------------
// Unit row = 16 floats = 64 B = 1 cache line. Lane l: edge j + (l>>2),
// channel-quad cg = l&3. 16 edges per round, one dwordx4 per lane.
// Slot g = blockIdx%8 (-> XCD round-robin): contiguous node-step range in
// unit-major order; resident window <= 2 unit buffers (~2.6 MB) -> L2-resident.
// ALL outputs use nontemporal (no-allocate) stores so L2 keeps only the
// gather source. Pair stream is nontemporal loads.
// level 1: 4 units (quarters of 64 ch), snap s=1, diffs {2,4,8,16} -> S1 slots 0..3.
// level 2: 12 units (S1 block sb=u>>2, quarter qu=u&3), snap 2<<sb,
//          diffs: sb0 {4,8,16}->{0,1,3}, sb1 {8,16}->{2,4}, sb2 {16}->{5}.

__global__ __launch_bounds__(256) void cascade_step_k(
    const float* __restrict__ src0,   // x (L1) or S1 (L2) for s==1
    const float* __restrict__ ubin,   // unit buffers in (s>1)
    float* __restrict__ ubout,
    const int2* __restrict__ pairs, const int* __restrict__ cnt,
    const float* __restrict__ dinv, int n,
    int s, int level,
    float* __restrict__ prevb, float* __restrict__ Sdst)
{
    int slot = blockIdx.x & 7, r = blockIdx.x >> 3;
    int lane = threadIdx.x & 63, widx = threadIdx.x >> 6;
    int U = (level == 1) ? 4 : 12;
    int per = (U * n) >> 3;             // node-steps per slot (n even)
    int pos = r * 4 + widx;
    if (pos >= per) return;
    int idx = slot * per + pos;
    int u = idx / n;
    int node = idx - u * n;
    u = __builtin_amdgcn_readfirstlane(u);
    node = __builtin_amdgcn_readfirstlane(node);
    int sb, qu;
    if (level == 1) { sb = 0; qu = u; }
    else            { sb = u >> 2; qu = u & 3; }

    const float* gb; int gstride;
    if (s == 1) {
        if (level == 1) { gb = src0 + qu * 16;           gstride = 64;  }
        else            { gb = src0 + sb * 64 + qu * 16; gstride = 256; }
    } else {
        gb = ubin + (size_t)u * n * 16; gstride = 16;
    }

    int deg = min(cnt[node], CAP);
    int deg16 = (deg + 15) & ~15;
    float dv = dinv[node];
    float selfw = 1.f + dv * dv;

    int sub = lane >> 2, cg = lane & 3;
    const long long* pb8 = reinterpret_cast<const long long*>(pairs + (size_t)node * CAP);

    vf4 acc = {0.f, 0.f, 0.f, 0.f};
    if (deg16 > 0) {
        long long pv = __builtin_nontemporal_load(pb8 + sub);
        int j = 0;
        while (true) {
            int srcn = (int)((unsigned long long)pv & 0xFFFFFFFFull);
            float w = __uint_as_float((unsigned int)((unsigned long long)pv >> 32));
            int jn = j + 16;
            bool more = jn < deg16;
            long long pn = 0;
            if (more) pn = __builtin_nontemporal_load(pb8 + jn + sub);
            vf4 g = *reinterpret_cast<const vf4*>(gb + (size_t)srcn * gstride + cg * 4);
            acc += w * g;
            if (!more) break;
            pv = pn; j = jn;
        }
    }
#pragma unroll
    for (int m = 4; m <= 32; m <<= 1) {
        acc.x += __shfl_xor(acc.x, m, 64);
        acc.y += __shfl_xor(acc.y, m, 64);
        acc.z += __shfl_xor(acc.z, m, 64);
        acc.w += __shfl_xor(acc.w, m, 64);
    }

    if (lane < 4) {
        vf4 hv = *reinterpret_cast<const vf4*>(gb + (size_t)node * gstride + cg * 4);
        vf4 v = 0.5f * (selfw * hv + acc);
        __builtin_nontemporal_store(v,
            reinterpret_cast<vf4*>(ubout + (size_t)u * n * 16 + (size_t)node * 16 + cg * 4));
        int snap = (level == 1) ? 1 : (2 << sb);
        vf4* prow = reinterpret_cast<vf4*>(prevb + (size_t)u * n * 16 + (size_t)node * 16 + cg * 4);
        if (s == snap) {
            __builtin_nontemporal_store(v, prow);
        } else if (s > snap && (s == 2 || s == 4 || s == 8 || s == 16)) {
            int slt;
            if (level == 1)   slt = (s == 2) ? 0 : (s == 4) ? 1 : (s == 8) ? 2 : 3;
            else if (sb == 0) slt = (s == 4) ? 0 : (s == 8) ? 1 : 3;
            else if (sb == 1) slt = (s == 8) ? 2 : 4;
            else              slt = 5;
            vf4 pv4 = __builtin_nontemporal_load(prow);
            __builtin_nontemporal_store(v, prow);
            vf4 d;
            d.x = fabsf(v.x - pv4.x); d.y = fabsf(v.y - pv4.y);
            d.z = fabsf(v.z - pv4.z); d.w = fabsf(v.w - pv4.w);
            int sstride = (level == 1) ? 256 : 384;
            __builtin_nontemporal_store(d,
                reinterpret_cast<vf4*>(Sdst + (size_t)node * sstride + slt * 64 + qu * 16 + cg * 4));
        }
    }
}

// ---------------- moments (coalesced two-stage, no atomics) ----------------

__global__ __launch_bounds__(256) void moments_part(
    const float* __restrict__ x, const float* __restrict__ S1,
    const float* __restrict__ S2, const int* __restrict__ boff,
    double* __restrict__ part)
{
    int bid = blockIdx.x;                    // b * (11*MSLICE) + k * MSLICE + slice
    int slice = bid % MSLICE;
    int k = (bid / MSLICE) % 11;
    int b = bid / (11 * MSLICE);
    int c = threadIdx.x & 63, sub = threadIdx.x >> 6;

    const float* base; int stride;
    if (k == 0)      { base = x  + c;                stride = 64;  }
    else if (k <= 4) { base = S1 + (k - 1) * 64 + c; stride = 256; }
    else             { base = S2 + (k - 5) * 64 + c; stride = 384; }

    int s0 = boff[b], s1e = boff[b + 1];
    int cntb = s1e - s0;
    int per = (cntb + MSLICE - 1) / MSLICE;
    int i0 = s0 + slice * per;
    int i1 = min(s1e, i0 + per);

    double a1 = 0, a2 = 0, a3 = 0, a4 = 0;
    for (int i = i0 + sub; i < i1; i += 4) {
        double v = (double)base[(size_t)i * stride];
        double qq = v * v;
        a1 += v; a2 += qq; a3 += qq * v; a4 += qq * qq;
    }
    int f = k * 64 + c;
    double* qp = part + ((((size_t)slice * 4 + sub) * NB + b) * NFEAT + f) * 4;
    qp[0] = a1; qp[1] = a2; qp[2] = a3; qp[3] = a4;
}

__global__ void finalize_k(const double* __restrict__ part, const int* __restrict__ boff,
                           const float* __restrict__ W, float* __restrict__ out) {
    int i = blockIdx.x * blockDim.x + threadIdx.x;
    if (i < NB * NFEAT) {
        int b = i / NFEAT, f = i % NFEAT;
        double s1 = 0, s2 = 0, s3 = 0, s4 = 0;
        for (int s = 0; s < PSLICE; ++s) {
            const double* qp = part + (((size_t)s * NB + b) * NFEAT + f) * 4;
            s1 += qp[0]; s2 += qp[1]; s3 += qp[2]; s4 += qp[3];
        }
        double cn = (double)max(boff[b + 1] - boff[b], 1);
        double mean = s1 / cn;
        double e2 = s2 / cn, e3 = s3 / cn, e4 = s4 / cn;
        double var = e2 - mean * mean;
        double m3 = e3 - 3.0 * mean * e2 + 2.0 * mean * mean * mean;
        double m4 = e4 - 4.0 * mean * e3 + 6.0 * mean * mean * e2 - 3.0 * mean * mean * mean * mean;
        float skew, kurt;
        if (var > 0.0) {
            double vs = var * sqrt(var);
            skew = (float)(m3 / vs);
            kurt = (float)(m4 / (var * var));
        } else {
            skew = 0.f; kurt = -3.f;
        }
        out[b * 2816 + f]        = (float)mean;
        out[b * 2816 + 704 + f]  = (float)var;
        out[b * 2816 + 1408 + f] = skew;
        out[b * 2816 + 2112 + f] = kurt;
    } else if (i < NB * NFEAT + 68) {
        int j = i - NB * NFEAT;
        out[NB * 2816 + j] = W[j];
    }
}

// ---------------- launch ----------------

extern "C" void kernel_launch(void* const* d_in, const int* in_sizes, int n_in,
                              void* d_out, int out_size, void* d_ws, size_t ws_size,
                              hipStream_t stream) {
    const float* x     = (const float*)d_in[0];
    const int*   ei    = (const int*)d_in[1];
    const int*   batch = (const int*)d_in[2];
    const float* W     = (const float*)d_in[3];
    int N = in_sizes[0] / 64;   // 20000
    int E = in_sizes[1] / 2;    // 640000
    float* out = (float*)d_out;

    char* p = (char*)d_ws;
    auto alloc = [&](size_t bytes) { char* r = p; p += (bytes + 255) & ~255ULL; return r; };
    float* dinv  = (float*)alloc((size_t)N * 4);
    int*   cnt   = (int*)alloc((size_t)N * 4);
    int*   cursor= (int*)alloc((size_t)N * 4);
    int*   boff  = (int*)alloc((NB + 1) * 4);
    double* part = (double*)alloc((size_t)PSLICE * NB * NFEAT * 4 * 8);
    int2*  pairs = (int2*)alloc((size_t)N * CAP * 8);
    float* S1    = (float*)alloc((size_t)N * 256 * 4);
    float* S2    = (float*)alloc((size_t)N * 384 * 4);
    float* bufA  = (float*)alloc((size_t)12 * N * 16 * 4);
    float* bufB  = (float*)alloc((size_t)12 * N * 16 * 4);
    float* prev  = (float*)alloc((size_t)12 * N * 16 * 4);

    hipMemsetAsync(cnt, 0, (size_t)N * 4, stream);
    hipMemsetAsync(cursor, 0, (size_t)N * 4, stream);

    count_edges<<<(E + 255) / 256, 256, 0, stream>>>(ei, E, cnt);
    compute_dinv<<<(N + 255) / 256, 256, 0, stream>>>(cnt, dinv, N);
    fill_edges<<<(E + 255) / 256, 256, 0, stream>>>(ei, E, dinv, cursor, pairs);
    pad_edges<<<(N + 255) / 256, 256, 0, stream>>>(cnt, pairs, N);
    batch_bounds<<<(N + 255) / 256, 256, 0, stream>>>(batch, N, boff);

    // grid: 8 slots * ceil(per/4) blocks, 4 waves (node-steps) per block
    int per1 = (4 * N) >> 3, per2 = (12 * N) >> 3;
    int grid1 = 8 * ((per1 + 3) >> 2);
    int grid2 = 8 * ((per2 + 3) >> 2);

    // ---- level 1: 4x16-ch units on x ----
    for (int s = 1; s <= 16; ++s) {
        float* ho = (s & 1) ? bufA : bufB;
        const float* hi = (s & 1) ? bufB : bufA;
        cascade_step_k<<<grid1, 256, 0, stream>>>(x, hi, ho, pairs, cnt, dinv, N,
                                                  s, 1, prev, S1);
    }
    // ---- level 2: 12x16-ch units on S1 ----
    for (int s = 1; s <= 16; ++s) {
        float* ho = (s & 1) ? bufA : bufB;
        const float* hi = (s & 1) ? bufB : bufA;
        cascade_step_k<<<grid2, 256, 0, stream>>>(S1, hi, ho, pairs, cnt, dinv, N,
                                                  s, 2, prev, S2);
    }

    moments_part<<<NB * 11 * MSLICE, 256, 0, stream>>>(x, S1, S2, boff, part);

    int fin_threads = NB * NFEAT + 68;
    finalize_k<<<(fin_threads + 255) / 256, 256, 0, stream>>>(part, boff, W, out);
}

// Round 8
// 1166.948 us; speedup vs baseline: 2.1958x; 2.1958x over previous
//
#include <hip/hip_runtime.h>
#include <hip/hip_fp16.h>

#define NB 8
#define CAP 128
#define NFEAT 704
#define MSLICE 8            // node slices per (batch,k) in moments
#define PSLICE (MSLICE * 4) // partial slots = slices * subs

// ---------------- setup kernels ----------------

__global__ void count_edges(const int* __restrict__ ei, int E, int* __restrict__ cnt) {
    int e = blockIdx.x * blockDim.x + threadIdx.x;
    if (e < E) atomicAdd(&cnt[ei[E + e]], 1);
}

__global__ void compute_dinv(const int* __restrict__ cnt, float* __restrict__ dinv, int n) {
    int v = blockIdx.x * blockDim.x + threadIdx.x;
    if (v < n) dinv[v] = rsqrtf((float)(cnt[v] + 1));  // +1 self-loop; always > 0
}

__global__ void fill_edges(const int* __restrict__ ei, int E, const float* __restrict__ dinv,
                           int* __restrict__ cursor, int2* __restrict__ pairs) {
    int e = blockIdx.x * blockDim.x + threadIdx.x;
    if (e < E) {
        int r = ei[e], c = ei[E + e];
        int pos = atomicAdd(&cursor[c], 1);
        if (pos < CAP) {
            float w = dinv[r] * dinv[c];
            pairs[(size_t)c * CAP + pos] = make_int2(r, __float_as_int(w));
        }
    }
}

// pad each node's edge list to a multiple of 4 with zero-weight edges
__global__ void pad_edges(const int* __restrict__ cnt, int2* __restrict__ pairs, int n) {
    int v = blockIdx.x * blockDim.x + threadIdx.x;
    if (v >= n) return;
    int c = min(cnt[v], CAP);
    int c4 = (c + 3) & ~3;
    for (int j = c; j < c4; ++j) pairs[(size_t)v * CAP + j] = make_int2(0, 0);
}

// batch is SORTED: boundaries, no atomics
__global__ void batch_bounds(const int* __restrict__ batch, int n, int* __restrict__ boff) {
    int i = blockIdx.x * blockDim.x + threadIdx.x;
    if (i >= n) return;
    int b = batch[i];
    int pb = (i == 0) ? -1 : batch[i - 1];
    for (int k = pb + 1; k <= b; ++k) boff[k] = i;
    if (i == n - 1) {
        for (int k = b + 1; k <= NB; ++k) boff[k] = n;
    }
}

__global__ void convert_f16(const float* __restrict__ x, unsigned short* __restrict__ xh, int n) {
    int i = blockIdx.x * blockDim.x + threadIdx.x;
    if (i < n) {
        __half h = __float2half_rn(x[i]);
        xh[i] = *reinterpret_cast<unsigned short*>(&h);
    }
}

// ---------------- cascade (64 channels per unit, one wave per node) ----------------
// h_out = 0.5*((1+dinv^2)*h_in + sum w*h_in[src]); gathers read the fp16 MIRROR
// of h_in (128 B row = 2 lines/edge); self term, outputs, diffs all fp32.
// Lane l: edge j + (l>>4), channels (l&15)*4 .. +3 (uint2 = 4 halves per gather).
// blockIdx.y = unit u (level 2: S1 wavelet blocks 0..2). Epilogue writes fp32
// state + fp16 mirror; snapshot/diff per (level,u,s) from fp32 prev.

__device__ __forceinline__ void fma_h4(float w, unsigned int lo, unsigned int hi,
                                       float& a0, float& a1, float& a2, float& a3) {
    float2 f0 = __half22float2(*reinterpret_cast<__half2*>(&lo));
    float2 f1 = __half22float2(*reinterpret_cast<__half2*>(&hi));
    a0 += w * f0.x; a1 += w * f0.y; a2 += w * f1.x; a3 += w * f1.y;
}

__global__ __launch_bounds__(256) void cascade_k(
    const float* __restrict__ selfp, int sstride, long usz,          // fp32 h_in (self term)
    const unsigned short* __restrict__ mirp, long musz,              // fp16 mirror of h_in
    float* __restrict__ state_out, unsigned short* __restrict__ mir_out,
    const int2* __restrict__ pairs, const int* __restrict__ cnt,
    const float* __restrict__ dinv, int n,
    int s, int level,
    float* __restrict__ prevb,
    float* __restrict__ S1, unsigned short* __restrict__ S1h,
    float* __restrict__ S2)
{
    int lane = threadIdx.x & 63, widx = threadIdx.x >> 6;
    int node = blockIdx.x * 4 + widx;
    if (node >= n) return;
    node = __builtin_amdgcn_readfirstlane(node);
    int u = blockIdx.y;

    int deg = min(cnt[node], CAP);
    int deg4 = (deg + 3) & ~3;
    float dv = dinv[node];
    float selfw = 1.f + dv * dv;

    int sub = lane >> 4;   // edge within group of 4
    int cg  = lane & 15;   // channel quad: ch cg*4 .. +3

    const unsigned short* mb = mirp + (size_t)u * musz;
    const int2* pb = pairs + (size_t)node * CAP;

    float a0 = 0.f, a1 = 0.f, a2 = 0.f, a3 = 0.f;
    int j = 0;
    for (; j + 8 <= deg4; j += 8) {
        int4 q0 = *reinterpret_cast<const int4*>(pb + j);
        int4 q1 = *reinterpret_cast<const int4*>(pb + j + 2);
        int4 q2 = *reinterpret_cast<const int4*>(pb + j + 4);
        int4 q3 = *reinterpret_cast<const int4*>(pb + j + 6);
        int   sA = sub < 2 ? (sub == 0 ? q0.x : q0.z) : (sub == 2 ? q1.x : q1.z);
        float wA = __int_as_float(sub < 2 ? (sub == 0 ? q0.y : q0.w) : (sub == 2 ? q1.y : q1.w));
        int   sB = sub < 2 ? (sub == 0 ? q2.x : q2.z) : (sub == 2 ? q3.x : q3.z);
        float wB = __int_as_float(sub < 2 ? (sub == 0 ? q2.y : q2.w) : (sub == 2 ? q3.y : q3.w));
        uint2 mA = *reinterpret_cast<const uint2*>(mb + (size_t)sA * 64 + cg * 4);
        uint2 mB = *reinterpret_cast<const uint2*>(mb + (size_t)sB * 64 + cg * 4);
        fma_h4(wA, mA.x, mA.y, a0, a1, a2, a3);
        fma_h4(wB, mB.x, mB.y, a0, a1, a2, a3);
    }
    if (j < deg4) {  // one remaining group of 4
        int4 q0 = *reinterpret_cast<const int4*>(pb + j);
        int4 q1 = *reinterpret_cast<const int4*>(pb + j + 2);
        int   sA = sub < 2 ? (sub == 0 ? q0.x : q0.z) : (sub == 2 ? q1.x : q1.z);
        float wA = __int_as_float(sub < 2 ? (sub == 0 ? q0.y : q0.w) : (sub == 2 ? q1.y : q1.w));
        uint2 mA = *reinterpret_cast<const uint2*>(mb + (size_t)sA * 64 + cg * 4);
        fma_h4(wA, mA.x, mA.y, a0, a1, a2, a3);
    }

    // reduce the 4 edge-phases: lanes {cg, cg+16, cg+32, cg+48} share channels
#pragma unroll
    for (int m = 16; m <= 32; m <<= 1) {
        a0 += __shfl_xor(a0, m, 64);
        a1 += __shfl_xor(a1, m, 64);
        a2 += __shfl_xor(a2, m, 64);
        a3 += __shfl_xor(a3, m, 64);
    }

    if (lane < 16) {
        const float* srow = selfp + (size_t)u * usz + (size_t)node * sstride + cg * 4;
        float4 hv = *reinterpret_cast<const float4*>(srow);
        float4 v;
        v.x = 0.5f * (selfw * hv.x + a0);
        v.y = 0.5f * (selfw * hv.y + a1);
        v.z = 0.5f * (selfw * hv.z + a2);
        v.w = 0.5f * (selfw * hv.w + a3);
        size_t oidx = (size_t)u * n * 64 + (size_t)node * 64 + cg * 4;
        *reinterpret_cast<float4*>(state_out + oidx) = v;
        __half2 p01 = __float22half2_rn(make_float2(v.x, v.y));
        __half2 p23 = __float22half2_rn(make_float2(v.z, v.w));
        uint2 mo;
        mo.x = *reinterpret_cast<unsigned int*>(&p01);
        mo.y = *reinterpret_cast<unsigned int*>(&p23);
        *reinterpret_cast<uint2*>(mir_out + oidx) = mo;

        int snap = (level == 1) ? 1 : (2 << u);
        float* prow = prevb + oidx;
        if (s == snap) {
            *reinterpret_cast<float4*>(prow) = v;
        } else if (s > snap && (s == 2 || s == 4 || s == 8 || s == 16)) {
            float4 pv = *reinterpret_cast<const float4*>(prow);
            *reinterpret_cast<float4*>(prow) = v;
            float4 d;
            d.x = fabsf(v.x - pv.x); d.y = fabsf(v.y - pv.y);
            d.z = fabsf(v.z - pv.z); d.w = fabsf(v.w - pv.w);
            if (level == 1) {
                int slot = (s == 2) ? 0 : (s == 4) ? 1 : (s == 8) ? 2 : 3;
                *reinterpret_cast<float4*>(S1 + (size_t)node * 256 + slot * 64 + cg * 4) = d;
                if (slot < 3) {
                    __half2 d01 = __float22half2_rn(make_float2(d.x, d.y));
                    __half2 d23 = __float22half2_rn(make_float2(d.z, d.w));
                    uint2 dh;
                    dh.x = *reinterpret_cast<unsigned int*>(&d01);
                    dh.y = *reinterpret_cast<unsigned int*>(&d23);
                    *reinterpret_cast<uint2*>(S1h + (size_t)slot * n * 64 + (size_t)node * 64 + cg * 4) = dh;
                }
            } else {
                int slt;
                if (u == 0)      slt = (s == 4) ? 0 : (s == 8) ? 1 : 3;
                else if (u == 1) slt = (s == 8) ? 2 : 4;
                else             slt = 5;
                *reinterpret_cast<float4*>(S2 + (size_t)node * 384 + slt * 64 + cg * 4) = d;
            }
        }
    }
}

// ---------------- moments (coalesced two-stage, no atomics) ----------------

__global__ __launch_bounds__(256) void moments_part(
    const float* __restrict__ x, const float* __restrict__ S1,
    const float* __restrict__ S2, const int* __restrict__ boff,
    double* __restrict__ part)
{
    int bid = blockIdx.x;                    // b * (11*MSLICE) + k * MSLICE + slice
    int slice = bid % MSLICE;
    int k = (bid / MSLICE) % 11;
    int b = bid / (11 * MSLICE);
    int c = threadIdx.x & 63, sub = threadIdx.x >> 6;

    const float* base; int stride;
    if (k == 0)      { base = x  + c;                stride = 64;  }
    else if (k <= 4) { base = S1 + (k - 1) * 64 + c; stride = 256; }
    else             { base = S2 + (k - 5) * 64 + c; stride = 384; }

    int s0 = boff[b], s1e = boff[b + 1];
    int cntb = s1e - s0;
    int per = (cntb + MSLICE - 1) / MSLICE;
    int i0 = s0 + slice * per;
    int i1 = min(s1e, i0 + per);

    double a1 = 0, a2 = 0, a3 = 0, a4 = 0;
    for (int i = i0 + sub; i < i1; i += 4) {
        double v = (double)base[(size_t)i * stride];
        double qq = v * v;
        a1 += v; a2 += qq; a3 += qq * v; a4 += qq * qq;
    }
    int f = k * 64 + c;
    double* qp = part + ((((size_t)slice * 4 + sub) * NB + b) * NFEAT + f) * 4;
    qp[0] = a1; qp[1] = a2; qp[2] = a3; qp[3] = a4;
}

__global__ void finalize_k(const double* __restrict__ part, const int* __restrict__ boff,
                           const float* __restrict__ W, float* __restrict__ out) {
    int i = blockIdx.x * blockDim.x + threadIdx.x;
    if (i < NB * NFEAT) {
        int b = i / NFEAT, f = i % NFEAT;
        double s1 = 0, s2 = 0, s3 = 0, s4 = 0;
        for (int s = 0; s < PSLICE; ++s) {
            const double* qp = part + (((size_t)s * NB + b) * NFEAT + f) * 4;
            s1 += qp[0]; s2 += qp[1]; s3 += qp[2]; s4 += qp[3];
        }
        double cn = (double)max(boff[b + 1] - boff[b], 1);
        double mean = s1 / cn;
        double e2 = s2 / cn, e3 = s3 / cn, e4 = s4 / cn;
        double var = e2 - mean * mean;
        double m3 = e3 - 3.0 * mean * e2 + 2.0 * mean * mean * mean;
        double m4 = e4 - 4.0 * mean * e3 + 6.0 * mean * mean * e2 - 3.0 * mean * mean * mean * mean;
        float skew, kurt;
        if (var > 0.0) {
            double vs = var * sqrt(var);
            skew = (float)(m3 / vs);
            kurt = (float)(m4 / (var * var));
        } else {
            skew = 0.f; kurt = -3.f;
        }
        out[b * 2816 + f]        = (float)mean;
        out[b * 2816 + 704 + f]  = (float)var;
        out[b * 2816 + 1408 + f] = skew;
        out[b * 2816 + 2112 + f] = kurt;
    } else if (i < NB * NFEAT + 68) {
        int j = i - NB * NFEAT;
        out[NB * 2816 + j] = W[j];
    }
}

// ---------------- launch ----------------

extern "C" void kernel_launch(void* const* d_in, const int* in_sizes, int n_in,
                              void* d_out, int out_size, void* d_ws, size_t ws_size,
                              hipStream_t stream) {
    const float* x     = (const float*)d_in[0];
    const int*   ei    = (const int*)d_in[1];
    const int*   batch = (const int*)d_in[2];
    const float* W     = (const float*)d_in[3];
    int N = in_sizes[0] / 64;   // 20000
    int E = in_sizes[1] / 2;    // 640000
    float* out = (float*)d_out;

    char* p = (char*)d_ws;
    auto alloc = [&](size_t bytes) { char* r = p; p += (bytes + 255) & ~255ULL; return r; };
    float* dinv  = (float*)alloc((size_t)N * 4);
    int*   cnt   = (int*)alloc((size_t)N * 4);
    int*   cursor= (int*)alloc((size_t)N * 4);
    int*   boff  = (int*)alloc((NB + 1) * 4);
    double* part = (double*)alloc((size_t)PSLICE * NB * NFEAT * 4 * 8);
    int2*  pairs = (int2*)alloc((size_t)N * CAP * 8);
    float* S1    = (float*)alloc((size_t)N * 256 * 4);
    float* S2    = (float*)alloc((size_t)N * 384 * 4);
    unsigned short* S1h = (unsigned short*)alloc((size_t)3 * N * 64 * 2);
    unsigned short* xh  = (unsigned short*)alloc((size_t)N * 64 * 2);
    float* bufA  = (float*)alloc((size_t)3 * N * 64 * 4);
    float* bufB  = (float*)alloc((size_t)3 * N * 64 * 4);
    float* prev  = (float*)alloc((size_t)3 * N * 64 * 4);
    unsigned short* mirA = (unsigned short*)alloc((size_t)3 * N * 64 * 2);
    unsigned short* mirB = (unsigned short*)alloc((size_t)3 * N * 64 * 2);

    hipMemsetAsync(cnt, 0, (size_t)N * 4, stream);
    hipMemsetAsync(cursor, 0, (size_t)N * 4, stream);

    count_edges<<<(E + 255) / 256, 256, 0, stream>>>(ei, E, cnt);
    compute_dinv<<<(N + 255) / 256, 256, 0, stream>>>(cnt, dinv, N);
    fill_edges<<<(E + 255) / 256, 256, 0, stream>>>(ei, E, dinv, cursor, pairs);
    pad_edges<<<(N + 255) / 256, 256, 0, stream>>>(cnt, pairs, N);
    batch_bounds<<<(N + 255) / 256, 256, 0, stream>>>(batch, N, boff);
    convert_f16<<<(N * 64 + 255) / 256, 256, 0, stream>>>(x, xh, N * 64);

    long nu = (long)N * 64;
    dim3 grid1((N + 3) / 4, 1);
    dim3 grid3((N + 3) / 4, 3);

    // ---- level 1: 64-ch cascade on x; snap s=1; diffs {2,4,8,16} -> S1 slots 0..3 (+S1h 0..2) ----
    for (int s = 1; s <= 16; ++s) {
        float* so = (s & 1) ? bufA : bufB;
        unsigned short* mo = (s & 1) ? mirA : mirB;
        const float* selfp; int sstride; long usz;
        const unsigned short* mirp; long musz;
        if (s == 1) { selfp = x; sstride = 64; usz = 0; mirp = xh; musz = 0; }
        else {
            selfp = (s & 1) ? bufB : bufA; sstride = 64; usz = nu;
            mirp = (s & 1) ? mirB : mirA; musz = nu;
        }
        cascade_k<<<grid1, 256, 0, stream>>>(selfp, sstride, usz, mirp, musz, so, mo,
                                             pairs, cnt, dinv, N, s, 1, prev, S1, S1h, S2);
    }

    // ---- level 2: 3x64-ch units (S1 wavelet blocks 0..2), merged; snap 2<<u;
    //      diffs: u0 {4,8,16}->S2 slots {0,1,3}, u1 {8,16}->{2,4}, u2 {16}->{5} ----
    for (int s = 1; s <= 16; ++s) {
        float* so = (s & 1) ? bufA : bufB;
        unsigned short* mo = (s & 1) ? mirA : mirB;
        const float* selfp; int sstride; long usz;
        const unsigned short* mirp; long musz;
        if (s == 1) { selfp = S1; sstride = 256; usz = 64; mirp = S1h; musz = nu; }
        else {
            selfp = (s & 1) ? bufB : bufA; sstride = 64; usz = nu;
            mirp = (s & 1) ? mirB : mirA; musz = nu;
        }
        cascade_k<<<grid3, 256, 0, stream>>>(selfp, sstride, usz, mirp, musz, so, mo,
                                             pairs, cnt, dinv, N, s, 2, prev, S1, S1h, S2);
    }

    moments_part<<<NB * 11 * MSLICE, 256, 0, stream>>>(x, S1, S2, boff, part);

    int fin_threads = NB * NFEAT + 68;
    finalize_k<<<(fin_threads + 255) / 256, 256, 0, stream>>>(part, boff, W, out);
}

// Round 9
// 939.915 us; speedup vs baseline: 2.7261x; 1.2415x over previous
//
#include <hip/hip_runtime.h>
#include <hip/hip_fp16.h>

#define NB 8
#define CAP 128
#define NFEAT 704
#define MSLICE 8            // node slices per (batch,k) in moments
#define PSLICE (MSLICE * 4) // partial slots = slices * subs

// ---------------- setup kernels ----------------

__global__ void count_edges(const int* __restrict__ ei, int E, int* __restrict__ cnt) {
    int e = blockIdx.x * blockDim.x + threadIdx.x;
    if (e < E) atomicAdd(&cnt[ei[E + e]], 1);
}

__global__ void compute_dinv(const int* __restrict__ cnt, float* __restrict__ dinv, int n) {
    int v = blockIdx.x * blockDim.x + threadIdx.x;
    if (v < n) dinv[v] = rsqrtf((float)(cnt[v] + 1));  // +1 self-loop; always > 0
}

// packed edge: low 16 = src node (N < 65536), high 16 = f16 weight
__global__ void fill_edges(const int* __restrict__ ei, int E, const float* __restrict__ dinv,
                           int* __restrict__ cursor, unsigned int* __restrict__ pairs) {
    int e = blockIdx.x * blockDim.x + threadIdx.x;
    if (e < E) {
        int r = ei[e], c = ei[E + e];
        int pos = atomicAdd(&cursor[c], 1);
        if (pos < CAP) {
            float w = dinv[r] * dinv[c];
            __half hw = __float2half_rn(w);
            unsigned short hb = *reinterpret_cast<unsigned short*>(&hw);
            pairs[(size_t)c * CAP + pos] = (unsigned int)(r & 0xFFFF) | ((unsigned int)hb << 16);
        }
    }
}

// pad each node's edge list to a multiple of 4 with zero-weight edges (src 0, w +0)
__global__ void pad_edges(const int* __restrict__ cnt, unsigned int* __restrict__ pairs, int n) {
    int v = blockIdx.x * blockDim.x + threadIdx.x;
    if (v >= n) return;
    int c = min(cnt[v], CAP);
    int c4 = (c + 3) & ~3;
    for (int j = c; j < c4; ++j) pairs[(size_t)v * CAP + j] = 0u;
}

// batch is SORTED: boundaries, no atomics
__global__ void batch_bounds(const int* __restrict__ batch, int n, int* __restrict__ boff) {
    int i = blockIdx.x * blockDim.x + threadIdx.x;
    if (i >= n) return;
    int b = batch[i];
    int pb = (i == 0) ? -1 : batch[i - 1];
    for (int k = pb + 1; k <= b; ++k) boff[k] = i;
    if (i == n - 1) {
        for (int k = b + 1; k <= NB; ++k) boff[k] = n;
    }
}

__global__ void convert_f16(const float* __restrict__ x, unsigned short* __restrict__ xh, int n) {
    int i = blockIdx.x * blockDim.x + threadIdx.x;
    if (i < n) {
        __half h = __float2half_rn(x[i]);
        xh[i] = *reinterpret_cast<unsigned short*>(&h);
    }
}

// ---------------- cascade (64 ch per unit, NU units per wave, one wave per node) ----------------
// h_out = 0.5*((1+dinv^2)*h_in + sum w*h_in[src]); gathers read the fp16 MIRROR of
// h_in (128 B row = 2 lines/edge/unit); self term, state, diffs all fp32.
// Lane l: edge-phase sub = l>>4, channel quad cg = l&15 (uint2 = 4 halves/gather).
// Packed 4 B pairs loaded ONCE per wave and shared across the NU units.
// NU=1: level 1 (on x / ping-pong). NU=3: level 2 (3 wavelet-block units merged).
// Snapshot step: level1 s=1; level2 unit u at s=2<<u. Diff steps {2,4,8,16}.

__device__ __forceinline__ float h2f16(unsigned short h) {
    __half hh = *reinterpret_cast<__half*>(&h);
    return __half2float(hh);
}

__device__ __forceinline__ void fma_h4(float w, uint2 m, float* a) {
    float2 f0 = __half22float2(*reinterpret_cast<__half2*>(&m.x));
    float2 f1 = __half22float2(*reinterpret_cast<__half2*>(&m.y));
    a[0] += w * f0.x; a[1] += w * f0.y; a[2] += w * f1.x; a[3] += w * f1.y;
}

template <int NU>
__global__ __launch_bounds__(256) void cascade_k(
    const float* __restrict__ selfp, int sstride, long usz,          // fp32 h_in (self term)
    const unsigned short* __restrict__ mirp, long musz,              // fp16 mirror of h_in
    float* __restrict__ state_out, unsigned short* __restrict__ mir_out,
    const unsigned int* __restrict__ pairs, const int* __restrict__ cnt,
    const float* __restrict__ dinv, int n,
    int s,
    float* __restrict__ prevb,
    float* __restrict__ S1, unsigned short* __restrict__ S1h,
    float* __restrict__ S2)
{
    int lane = threadIdx.x & 63, widx = threadIdx.x >> 6;
    int node = blockIdx.x * 4 + widx;
    if (node >= n) return;
    node = __builtin_amdgcn_readfirstlane(node);

    int deg = min(cnt[node], CAP);
    int deg4 = (deg + 3) & ~3;
    float dv = dinv[node];
    float selfw = 1.f + dv * dv;

    int sub = lane >> 4;   // edge within group of 4
    int cg  = lane & 15;   // channel quad: ch cg*4 .. +3

    const unsigned int* pb = pairs + (size_t)node * CAP;

    float a[NU][4];
#pragma unroll
    for (int u = 0; u < NU; ++u)
#pragma unroll
        for (int k = 0; k < 4; ++k) a[u][k] = 0.f;

    int j = 0;
    for (; j + 8 <= deg4; j += 8) {
        uint4 qA = *reinterpret_cast<const uint4*>(pb + j);
        uint4 qB = *reinterpret_cast<const uint4*>(pb + j + 4);
        unsigned int eA = sub < 2 ? (sub == 0 ? qA.x : qA.y) : (sub == 2 ? qA.z : qA.w);
        unsigned int eB = sub < 2 ? (sub == 0 ? qB.x : qB.y) : (sub == 2 ? qB.z : qB.w);
        int   sA = (int)(eA & 0xFFFFu);
        float wA = h2f16((unsigned short)(eA >> 16));
        int   sB = (int)(eB & 0xFFFFu);
        float wB = h2f16((unsigned short)(eB >> 16));
        uint2 gA[NU], gB[NU];
#pragma unroll
        for (int u = 0; u < NU; ++u)
            gA[u] = *reinterpret_cast<const uint2*>(mirp + (size_t)u * musz + (size_t)sA * 64 + cg * 4);
#pragma unroll
        for (int u = 0; u < NU; ++u)
            gB[u] = *reinterpret_cast<const uint2*>(mirp + (size_t)u * musz + (size_t)sB * 64 + cg * 4);
#pragma unroll
        for (int u = 0; u < NU; ++u) {
            fma_h4(wA, gA[u], a[u]);
            fma_h4(wB, gB[u], a[u]);
        }
    }
    if (j < deg4) {  // one remaining group of 4
        uint4 qA = *reinterpret_cast<const uint4*>(pb + j);
        unsigned int eA = sub < 2 ? (sub == 0 ? qA.x : qA.y) : (sub == 2 ? qA.z : qA.w);
        int   sA = (int)(eA & 0xFFFFu);
        float wA = h2f16((unsigned short)(eA >> 16));
        uint2 gA[NU];
#pragma unroll
        for (int u = 0; u < NU; ++u)
            gA[u] = *reinterpret_cast<const uint2*>(mirp + (size_t)u * musz + (size_t)sA * 64 + cg * 4);
#pragma unroll
        for (int u = 0; u < NU; ++u) fma_h4(wA, gA[u], a[u]);
    }

    // reduce the 4 edge-phases: lanes {cg, cg+16, cg+32, cg+48} share channels
#pragma unroll
    for (int m = 16; m <= 32; m <<= 1) {
#pragma unroll
        for (int u = 0; u < NU; ++u) {
#pragma unroll
            for (int k = 0; k < 4; ++k) a[u][k] += __shfl_xor(a[u][k], m, 64);
        }
    }

    if (lane < 16) {
#pragma unroll
        for (int u = 0; u < NU; ++u) {
            const float* srow = selfp + (size_t)u * usz + (size_t)node * sstride + cg * 4;
            float4 hv = *reinterpret_cast<const float4*>(srow);
            float4 v;
            v.x = 0.5f * (selfw * hv.x + a[u][0]);
            v.y = 0.5f * (selfw * hv.y + a[u][1]);
            v.z = 0.5f * (selfw * hv.z + a[u][2]);
            v.w = 0.5f * (selfw * hv.w + a[u][3]);
            size_t oidx = (size_t)u * n * 64 + (size_t)node * 64 + cg * 4;
            *reinterpret_cast<float4*>(state_out + oidx) = v;
            __half2 p01 = __float22half2_rn(make_float2(v.x, v.y));
            __half2 p23 = __float22half2_rn(make_float2(v.z, v.w));
            uint2 mo;
            mo.x = *reinterpret_cast<unsigned int*>(&p01);
            mo.y = *reinterpret_cast<unsigned int*>(&p23);
            *reinterpret_cast<uint2*>(mir_out + oidx) = mo;

            int snap = (NU == 1) ? 1 : (2 << u);
            float* prow = prevb + oidx;
            if (s == snap) {
                *reinterpret_cast<float4*>(prow) = v;
            } else if (s > snap && (s == 2 || s == 4 || s == 8 || s == 16)) {
                float4 pv = *reinterpret_cast<const float4*>(prow);
                *reinterpret_cast<float4*>(prow) = v;
                float4 d;
                d.x = fabsf(v.x - pv.x); d.y = fabsf(v.y - pv.y);
                d.z = fabsf(v.z - pv.z); d.w = fabsf(v.w - pv.w);
                if (NU == 1) {
                    int slot = (s == 2) ? 0 : (s == 4) ? 1 : (s == 8) ? 2 : 3;
                    *reinterpret_cast<float4*>(S1 + (size_t)node * 256 + slot * 64 + cg * 4) = d;
                    if (slot < 3) {
                        __half2 d01 = __float22half2_rn(make_float2(d.x, d.y));
                        __half2 d23 = __float22half2_rn(make_float2(d.z, d.w));
                        uint2 dh;
                        dh.x = *reinterpret_cast<unsigned int*>(&d01);
                        dh.y = *reinterpret_cast<unsigned int*>(&d23);
                        *reinterpret_cast<uint2*>(S1h + (size_t)slot * n * 64 + (size_t)node * 64 + cg * 4) = dh;
                    }
                } else {
                    int slt;
                    if (u == 0)      slt = (s == 4) ? 0 : (s == 8) ? 1 : 3;
                    else if (u == 1) slt = (s == 8) ? 2 : 4;
                    else             slt = 5;
                    *reinterpret_cast<float4*>(S2 + (size_t)node * 384 + slt * 64 + cg * 4) = d;
                }
            }
        }
    }
}

// ---------------- moments (coalesced two-stage, no atomics) ----------------

__global__ __launch_bounds__(256) void moments_part(
    const float* __restrict__ x, const float* __restrict__ S1,
    const float* __restrict__ S2, const int* __restrict__ boff,
    double* __restrict__ part)
{
    int bid = blockIdx.x;                    // b * (11*MSLICE) + k * MSLICE + slice
    int slice = bid % MSLICE;
    int k = (bid / MSLICE) % 11;
    int b = bid / (11 * MSLICE);
    int c = threadIdx.x & 63, sub = threadIdx.x >> 6;

    const float* base; int stride;
    if (k == 0)      { base = x  + c;                stride = 64;  }
    else if (k <= 4) { base = S1 + (k - 1) * 64 + c; stride = 256; }
    else             { base = S2 + (k - 5) * 64 + c; stride = 384; }

    int s0 = boff[b], s1e = boff[b + 1];
    int cntb = s1e - s0;
    int per = (cntb + MSLICE - 1) / MSLICE;
    int i0 = s0 + slice * per;
    int i1 = min(s1e, i0 + per);

    double a1 = 0, a2 = 0, a3 = 0, a4 = 0;
    for (int i = i0 + sub; i < i1; i += 4) {
        double v = (double)base[(size_t)i * stride];
        double qq = v * v;
        a1 += v; a2 += qq; a3 += qq * v; a4 += qq * qq;
    }
    int f = k * 64 + c;
    double* qp = part + ((((size_t)slice * 4 + sub) * NB + b) * NFEAT + f) * 4;
    qp[0] = a1; qp[1] = a2; qp[2] = a3; qp[3] = a4;
}

__global__ void finalize_k(const double* __restrict__ part, const int* __restrict__ boff,
                           const float* __restrict__ W, float* __restrict__ out) {
    int i = blockIdx.x * blockDim.x + threadIdx.x;
    if (i < NB * NFEAT) {
        int b = i / NFEAT, f = i % NFEAT;
        double s1 = 0, s2 = 0, s3 = 0, s4 = 0;
        for (int s = 0; s < PSLICE; ++s) {
            const double* qp = part + (((size_t)s * NB + b) * NFEAT + f) * 4;
            s1 += qp[0]; s2 += qp[1]; s3 += qp[2]; s4 += qp[3];
        }
        double cn = (double)max(boff[b + 1] - boff[b], 1);
        double mean = s1 / cn;
        double e2 = s2 / cn, e3 = s3 / cn, e4 = s4 / cn;
        double var = e2 - mean * mean;
        double m3 = e3 - 3.0 * mean * e2 + 2.0 * mean * mean * mean;
        double m4 = e4 - 4.0 * mean * e3 + 6.0 * mean * mean * e2 - 3.0 * mean * mean * mean * mean;
        float skew, kurt;
        if (var > 0.0) {
            double vs = var * sqrt(var);
            skew = (float)(m3 / vs);
            kurt = (float)(m4 / (var * var));
        } else {
            skew = 0.f; kurt = -3.f;
        }
        out[b * 2816 + f]        = (float)mean;
        out[b * 2816 + 704 + f]  = (float)var;
        out[b * 2816 + 1408 + f] = skew;
        out[b * 2816 + 2112 + f] = kurt;
    } else if (i < NB * NFEAT + 68) {
        int j = i - NB * NFEAT;
        out[NB * 2816 + j] = W[j];
    }
}

// ---------------- launch ----------------

extern "C" void kernel_launch(void* const* d_in, const int* in_sizes, int n_in,
                              void* d_out, int out_size, void* d_ws, size_t ws_size,
                              hipStream_t stream) {
    const float* x     = (const float*)d_in[0];
    const int*   ei    = (const int*)d_in[1];
    const int*   batch = (const int*)d_in[2];
    const float* W     = (const float*)d_in[3];
    int N = in_sizes[0] / 64;   // 20000
    int E = in_sizes[1] / 2;    // 640000
    float* out = (float*)d_out;

    char* p = (char*)d_ws;
    auto alloc = [&](size_t bytes) { char* r = p; p += (bytes + 255) & ~255ULL; return r; };
    float* dinv  = (float*)alloc((size_t)N * 4);
    int*   cnt   = (int*)alloc((size_t)N * 4);
    int*   cursor= (int*)alloc((size_t)N * 4);
    int*   boff  = (int*)alloc((NB + 1) * 4);
    double* part = (double*)alloc((size_t)PSLICE * NB * NFEAT * 4 * 8);
    unsigned int* pairs = (unsigned int*)alloc((size_t)N * CAP * 4);
    float* S1    = (float*)alloc((size_t)N * 256 * 4);
    float* S2    = (float*)alloc((size_t)N * 384 * 4);
    unsigned short* S1h = (unsigned short*)alloc((size_t)3 * N * 64 * 2);
    unsigned short* xh  = (unsigned short*)alloc((size_t)N * 64 * 2);
    float* bufA  = (float*)alloc((size_t)3 * N * 64 * 4);
    float* bufB  = (float*)alloc((size_t)3 * N * 64 * 4);
    float* prev  = (float*)alloc((size_t)3 * N * 64 * 4);
    unsigned short* mirA = (unsigned short*)alloc((size_t)3 * N * 64 * 2);
    unsigned short* mirB = (unsigned short*)alloc((size_t)3 * N * 64 * 2);

    hipMemsetAsync(cnt, 0, (size_t)N * 4, stream);
    hipMemsetAsync(cursor, 0, (size_t)N * 4, stream);

    count_edges<<<(E + 255) / 256, 256, 0, stream>>>(ei, E, cnt);
    compute_dinv<<<(N + 255) / 256, 256, 0, stream>>>(cnt, dinv, N);
    fill_edges<<<(E + 255) / 256, 256, 0, stream>>>(ei, E, dinv, cursor, pairs);
    pad_edges<<<(N + 255) / 256, 256, 0, stream>>>(cnt, pairs, N);
    batch_bounds<<<(N + 255) / 256, 256, 0, stream>>>(batch, N, boff);
    convert_f16<<<(N * 64 + 255) / 256, 256, 0, stream>>>(x, xh, N * 64);

    long nu = (long)N * 64;
    int cgrid = (N + 3) / 4;

    // ---- level 1: 64-ch cascade on x; snap s=1; diffs {2,4,8,16} -> S1 slots 0..3 (+S1h 0..2) ----
    for (int s = 1; s <= 16; ++s) {
        float* so = (s & 1) ? bufA : bufB;
        unsigned short* mo = (s & 1) ? mirA : mirB;
        const float* selfp; int sstride; long usz;
        const unsigned short* mirp; long musz;
        if (s == 1) { selfp = x; sstride = 64; usz = 0; mirp = xh; musz = 0; }
        else {
            selfp = (s & 1) ? bufB : bufA; sstride = 64; usz = nu;
            mirp = (s & 1) ? mirB : mirA; musz = nu;
        }
        cascade_k<1><<<cgrid, 256, 0, stream>>>(selfp, sstride, usz, mirp, musz, so, mo,
                                                pairs, cnt, dinv, N, s, prev, S1, S1h, S2);
    }

    // ---- level 2: 3x64-ch units merged in one wave; snap 2<<u;
    //      diffs: u0 {4,8,16}->S2 {0,1,3}, u1 {8,16}->{2,4}, u2 {16}->{5} ----
    for (int s = 1; s <= 16; ++s) {
        float* so = (s & 1) ? bufA : bufB;
        unsigned short* mo = (s & 1) ? mirA : mirB;
        const float* selfp; int sstride; long usz;
        const unsigned short* mirp; long musz;
        if (s == 1) { selfp = S1; sstride = 256; usz = 64; mirp = S1h; musz = nu; }
        else {
            selfp = (s & 1) ? bufB : bufA; sstride = 64; usz = nu;
            mirp = (s & 1) ? mirB : mirA; musz = nu;
        }
        cascade_k<3><<<cgrid, 256, 0, stream>>>(selfp, sstride, usz, mirp, musz, so, mo,
                                                pairs, cnt, dinv, N, s, prev, S1, S1h, S2);
    }

    moments_part<<<NB * 11 * MSLICE, 256, 0, stream>>>(x, S1, S2, boff, part);

    int fin_threads = NB * NFEAT + 68;
    finalize_k<<<(fin_threads + 255) / 256, 256, 0, stream>>>(part, boff, W, out);
}

// Round 10
// 894.727 us; speedup vs baseline: 2.8638x; 1.0505x over previous
//
#include <hip/hip_runtime.h>
#include <hip/hip_fp16.h>

#define NB 8
#define CAP 128
#define NFEAT 704
#define MSLICE 8            // node slices per (batch,k) in moments
#define PSLICE (MSLICE * 4) // partial slots = slices * subs

// ---------------- setup kernels ----------------

__global__ void count_edges(const int* __restrict__ ei, int E, int* __restrict__ cnt) {
    int e = blockIdx.x * blockDim.x + threadIdx.x;
    if (e < E) atomicAdd(&cnt[ei[E + e]], 1);
}

__global__ void compute_dinv(const int* __restrict__ cnt, float* __restrict__ dinv, int n) {
    int v = blockIdx.x * blockDim.x + threadIdx.x;
    if (v < n) dinv[v] = rsqrtf((float)(cnt[v] + 1));  // +1 self-loop; always > 0
}

// packed edge: low 16 = src node (N < 65536), high 16 = f16 weight
__global__ void fill_edges(const int* __restrict__ ei, int E, const float* __restrict__ dinv,
                           int* __restrict__ cursor, unsigned int* __restrict__ pairs) {
    int e = blockIdx.x * blockDim.x + threadIdx.x;
    if (e < E) {
        int r = ei[e], c = ei[E + e];
        int pos = atomicAdd(&cursor[c], 1);
        if (pos < CAP) {
            float w = dinv[r] * dinv[c];
            __half hw = __float2half_rn(w);
            unsigned short hb = *reinterpret_cast<unsigned short*>(&hw);
            pairs[(size_t)c * CAP + pos] = (unsigned int)(r & 0xFFFF) | ((unsigned int)hb << 16);
        }
    }
}

// pad each node's edge list to a multiple of 8 with zero-weight edges (src 0, w +0)
__global__ void pad_edges(const int* __restrict__ cnt, unsigned int* __restrict__ pairs, int n) {
    int v = blockIdx.x * blockDim.x + threadIdx.x;
    if (v >= n) return;
    int c = min(cnt[v], CAP);
    int c8 = (c + 7) & ~7;
    for (int j = c; j < c8; ++j) pairs[(size_t)v * CAP + j] = 0u;
}

// batch is SORTED: boundaries, no atomics
__global__ void batch_bounds(const int* __restrict__ batch, int n, int* __restrict__ boff) {
    int i = blockIdx.x * blockDim.x + threadIdx.x;
    if (i >= n) return;
    int b = batch[i];
    int pb = (i == 0) ? -1 : batch[i - 1];
    for (int k = pb + 1; k <= b; ++k) boff[k] = i;
    if (i == n - 1) {
        for (int k = b + 1; k <= NB; ++k) boff[k] = n;
    }
}

__global__ void convert_f16(const float* __restrict__ x, unsigned short* __restrict__ xh, int n) {
    int i = blockIdx.x * blockDim.x + threadIdx.x;
    if (i < n) {
        __half h = __float2half_rn(x[i]);
        xh[i] = *reinterpret_cast<unsigned short*>(&h);
    }
}

// ---------------- cascade (U1 L1-units + U2 L2-units per wave, one wave per node) --------
// h_out = 0.5*((1+dinv^2)*h_in + sum w*h_in[src]); gathers read fp16 MIRRORS
// (128 B/row/unit); self term, state, diffs fp32. Lane l: edge-phase sub=l>>4,
// channel quad cg=l&15 (uint2 = 4 halves/gather). Packed 4 B pairs loaded once
// per wave, shared by all U1+U2 units; next 8-edge pair group PREFETCHED before
// the current group's gathers (breaks pair->gather serial chain).
// L1 snap s=1, diffs {2,4,8,16}->S1 slots 0..3 (+f16 S1h slots 0..2).
// L2 unit u: snap s=2<<u, diffs later {4,8,16}->S2 slots.
// Instantiations: <1,0> L1-only, <1,3> fused (L1 step s1 = s2+8), <0,3> L2-only.

__device__ __forceinline__ float h2f16(unsigned short h) {
    __half hh = *reinterpret_cast<__half*>(&h);
    return __half2float(hh);
}

__device__ __forceinline__ void fma_h4(float w, uint2 m, float* a) {
    float2 f0 = __half22float2(*reinterpret_cast<__half2*>(&m.x));
    float2 f1 = __half22float2(*reinterpret_cast<__half2*>(&m.y));
    a[0] += w * f0.x; a[1] += w * f0.y; a[2] += w * f1.x; a[3] += w * f1.y;
}

__device__ __forceinline__ uint2 pack_h4(float4 v) {
    __half2 p01 = __float22half2_rn(make_float2(v.x, v.y));
    __half2 p23 = __float22half2_rn(make_float2(v.z, v.w));
    uint2 r;
    r.x = *reinterpret_cast<unsigned int*>(&p01);
    r.y = *reinterpret_cast<unsigned int*>(&p23);
    return r;
}

template <int U1, int U2>
__global__ __launch_bounds__(256) void cascade_k(
    const float* __restrict__ self1, const unsigned short* __restrict__ mir1,
    float* __restrict__ state1o, unsigned short* __restrict__ mir1o,
    float* __restrict__ prev1, int s1,
    const float* __restrict__ self2, int sstride2, long usz2,
    const unsigned short* __restrict__ mir2, long musz2,
    float* __restrict__ state2o, unsigned short* __restrict__ mir2o,
    float* __restrict__ prev2, int s2,
    const unsigned int* __restrict__ pairs, const int* __restrict__ cnt,
    const float* __restrict__ dinv, int n,
    float* __restrict__ S1, unsigned short* __restrict__ S1h,
    float* __restrict__ S2)
{
    int lane = threadIdx.x & 63, widx = threadIdx.x >> 6;
    int node = blockIdx.x * 4 + widx;
    if (node >= n) return;
    node = __builtin_amdgcn_readfirstlane(node);

    int deg = min(cnt[node], CAP);
    int deg8 = (deg + 7) & ~7;
    float dv = dinv[node];
    float selfw = 1.f + dv * dv;

    int sub = lane >> 4;   // edge within group of 4
    int cg  = lane & 15;   // channel quad: ch cg*4 .. +3

    const unsigned int* pb = pairs + (size_t)node * CAP;

    float a1[U1 ? U1 : 1][4], a2[U2 ? U2 : 1][4];
#pragma unroll
    for (int u = 0; u < (U1 ? U1 : 1); ++u)
#pragma unroll
        for (int k = 0; k < 4; ++k) a1[u][k] = 0.f;
#pragma unroll
    for (int u = 0; u < (U2 ? U2 : 1); ++u)
#pragma unroll
        for (int k = 0; k < 4; ++k) a2[u][k] = 0.f;

    if (deg8 > 0) {
        uint4 qA = *reinterpret_cast<const uint4*>(pb);
        uint4 qB = *reinterpret_cast<const uint4*>(pb + 4);
        int j = 0;
        while (true) {
            int jn = j + 8;
            bool more = jn < deg8;
            uint4 nA, nB;
            if (more) {  // prefetch next pair group before consuming this one
                nA = *reinterpret_cast<const uint4*>(pb + jn);
                nB = *reinterpret_cast<const uint4*>(pb + jn + 4);
            }
            unsigned int eA = sub < 2 ? (sub == 0 ? qA.x : qA.y) : (sub == 2 ? qA.z : qA.w);
            unsigned int eB = sub < 2 ? (sub == 0 ? qB.x : qB.y) : (sub == 2 ? qB.z : qB.w);
            int   sA = (int)(eA & 0xFFFFu);
            float wA = h2f16((unsigned short)(eA >> 16));
            int   sB = (int)(eB & 0xFFFFu);
            float wB = h2f16((unsigned short)(eB >> 16));
            // issue all gathers, then all FMAs
            uint2 g1A, g1B, g2A[U2 ? U2 : 1], g2B[U2 ? U2 : 1];
            if (U1) {
                g1A = *reinterpret_cast<const uint2*>(mir1 + (size_t)sA * 64 + cg * 4);
                g1B = *reinterpret_cast<const uint2*>(mir1 + (size_t)sB * 64 + cg * 4);
            }
#pragma unroll
            for (int u = 0; u < U2; ++u)
                g2A[u] = *reinterpret_cast<const uint2*>(mir2 + (size_t)u * musz2 + (size_t)sA * 64 + cg * 4);
#pragma unroll
            for (int u = 0; u < U2; ++u)
                g2B[u] = *reinterpret_cast<const uint2*>(mir2 + (size_t)u * musz2 + (size_t)sB * 64 + cg * 4);
            if (U1) { fma_h4(wA, g1A, a1[0]); fma_h4(wB, g1B, a1[0]); }
#pragma unroll
            for (int u = 0; u < U2; ++u) {
                fma_h4(wA, g2A[u], a2[u]);
                fma_h4(wB, g2B[u], a2[u]);
            }
            if (!more) break;
            qA = nA; qB = nB; j = jn;
        }
    }

    // reduce the 4 edge-phases: lanes {cg, cg+16, cg+32, cg+48} share channels
#pragma unroll
    for (int m = 16; m <= 32; m <<= 1) {
#pragma unroll
        for (int u = 0; u < U1; ++u)
#pragma unroll
            for (int k = 0; k < 4; ++k) a1[u][k] += __shfl_xor(a1[u][k], m, 64);
#pragma unroll
        for (int u = 0; u < U2; ++u)
#pragma unroll
            for (int k = 0; k < 4; ++k) a2[u][k] += __shfl_xor(a2[u][k], m, 64);
    }

    if (lane < 16) {
        if (U1) {
            float4 hv = *reinterpret_cast<const float4*>(self1 + (size_t)node * 64 + cg * 4);
            float4 v;
            v.x = 0.5f * (selfw * hv.x + a1[0][0]);
            v.y = 0.5f * (selfw * hv.y + a1[0][1]);
            v.z = 0.5f * (selfw * hv.z + a1[0][2]);
            v.w = 0.5f * (selfw * hv.w + a1[0][3]);
            size_t oidx = (size_t)node * 64 + cg * 4;
            *reinterpret_cast<float4*>(state1o + oidx) = v;
            *reinterpret_cast<uint2*>(mir1o + oidx) = pack_h4(v);
            float* prow = prev1 + oidx;
            if (s1 == 1) {
                *reinterpret_cast<float4*>(prow) = v;
            } else if (s1 == 2 || s1 == 4 || s1 == 8 || s1 == 16) {
                float4 pv = *reinterpret_cast<const float4*>(prow);
                *reinterpret_cast<float4*>(prow) = v;
                float4 d;
                d.x = fabsf(v.x - pv.x); d.y = fabsf(v.y - pv.y);
                d.z = fabsf(v.z - pv.z); d.w = fabsf(v.w - pv.w);
                int slot = (s1 == 2) ? 0 : (s1 == 4) ? 1 : (s1 == 8) ? 2 : 3;
                *reinterpret_cast<float4*>(S1 + (size_t)node * 256 + slot * 64 + cg * 4) = d;
                if (slot < 3)
                    *reinterpret_cast<uint2*>(S1h + (size_t)slot * n * 64 + oidx) = pack_h4(d);
            }
        }
#pragma unroll
        for (int u = 0; u < U2; ++u) {
            const float* srow = self2 + (size_t)u * usz2 + (size_t)node * sstride2 + cg * 4;
            float4 hv = *reinterpret_cast<const float4*>(srow);
            float4 v;
            v.x = 0.5f * (selfw * hv.x + a2[u][0]);
            v.y = 0.5f * (selfw * hv.y + a2[u][1]);
            v.z = 0.5f * (selfw * hv.z + a2[u][2]);
            v.w = 0.5f * (selfw * hv.w + a2[u][3]);
            size_t oidx = (size_t)u * n * 64 + (size_t)node * 64 + cg * 4;
            *reinterpret_cast<float4*>(state2o + oidx) = v;
            *reinterpret_cast<uint2*>(mir2o + oidx) = pack_h4(v);
            int snap = 2 << u;
            float* prow = prev2 + oidx;
            if (s2 == snap) {
                *reinterpret_cast<float4*>(prow) = v;
            } else if (s2 > snap && (s2 == 4 || s2 == 8 || s2 == 16)) {
                float4 pv = *reinterpret_cast<const float4*>(prow);
                *reinterpret_cast<float4*>(prow) = v;
                float4 d;
                d.x = fabsf(v.x - pv.x); d.y = fabsf(v.y - pv.y);
                d.z = fabsf(v.z - pv.z); d.w = fabsf(v.w - pv.w);
                int slt;
                if (u == 0)      slt = (s2 == 4) ? 0 : (s2 == 8) ? 1 : 3;
                else if (u == 1) slt = (s2 == 8) ? 2 : 4;
                else             slt = 5;
                *reinterpret_cast<float4*>(S2 + (size_t)node * 384 + slt * 64 + cg * 4) = d;
            }
        }
    }
}

// ---------------- moments (coalesced two-stage, no atomics) ----------------

__global__ __launch_bounds__(256) void moments_part(
    const float* __restrict__ x, const float* __restrict__ S1,
    const float* __restrict__ S2, const int* __restrict__ boff,
    double* __restrict__ part)
{
    int bid = blockIdx.x;                    // b * (11*MSLICE) + k * MSLICE + slice
    int slice = bid % MSLICE;
    int k = (bid / MSLICE) % 11;
    int b = bid / (11 * MSLICE);
    int c = threadIdx.x & 63, sub = threadIdx.x >> 6;

    const float* base; int stride;
    if (k == 0)      { base = x  + c;                stride = 64;  }
    else if (k <= 4) { base = S1 + (k - 1) * 64 + c; stride = 256; }
    else             { base = S2 + (k - 5) * 64 + c; stride = 384; }

    int s0 = boff[b], s1e = boff[b + 1];
    int cntb = s1e - s0;
    int per = (cntb + MSLICE - 1) / MSLICE;
    int i0 = s0 + slice * per;
    int i1 = min(s1e, i0 + per);

    double a1 = 0, a2 = 0, a3 = 0, a4 = 0;
    for (int i = i0 + sub; i < i1; i += 4) {
        double v = (double)base[(size_t)i * stride];
        double qq = v * v;
        a1 += v; a2 += qq; a3 += qq * v; a4 += qq * qq;
    }
    int f = k * 64 + c;
    double* qp = part + ((((size_t)slice * 4 + sub) * NB + b) * NFEAT + f) * 4;
    qp[0] = a1; qp[1] = a2; qp[2] = a3; qp[3] = a4;
}

__global__ void finalize_k(const double* __restrict__ part, const int* __restrict__ boff,
                           const float* __restrict__ W, float* __restrict__ out) {
    int i = blockIdx.x * blockDim.x + threadIdx.x;
    if (i < NB * NFEAT) {
        int b = i / NFEAT, f = i % NFEAT;
        double s1 = 0, s2 = 0, s3 = 0, s4 = 0;
        for (int s = 0; s < PSLICE; ++s) {
            const double* qp = part + (((size_t)s * NB + b) * NFEAT + f) * 4;
            s1 += qp[0]; s2 += qp[1]; s3 += qp[2]; s4 += qp[3];
        }
        double cn = (double)max(boff[b + 1] - boff[b], 1);
        double mean = s1 / cn;
        double e2 = s2 / cn, e3 = s3 / cn, e4 = s4 / cn;
        double var = e2 - mean * mean;
        double m3 = e3 - 3.0 * mean * e2 + 2.0 * mean * mean * mean;
        double m4 = e4 - 4.0 * mean * e3 + 6.0 * mean * mean * e2 - 3.0 * mean * mean * mean * mean;
        float skew, kurt;
        if (var > 0.0) {
            double vs = var * sqrt(var);
            skew = (float)(m3 / vs);
            kurt = (float)(m4 / (var * var));
        } else {
            skew = 0.f; kurt = -3.f;
        }
        out[b * 2816 + f]        = (float)mean;
        out[b * 2816 + 704 + f]  = (float)var;
        out[b * 2816 + 1408 + f] = skew;
        out[b * 2816 + 2112 + f] = kurt;
    } else if (i < NB * NFEAT + 68) {
        int j = i - NB * NFEAT;
        out[NB * 2816 + j] = W[j];
    }
}

// ---------------- launch ----------------

extern "C" void kernel_launch(void* const* d_in, const int* in_sizes, int n_in,
                              void* d_out, int out_size, void* d_ws, size_t ws_size,
                              hipStream_t stream) {
    const float* x     = (const float*)d_in[0];
    const int*   ei    = (const int*)d_in[1];
    const int*   batch = (const int*)d_in[2];
    const float* W     = (const float*)d_in[3];
    int N = in_sizes[0] / 64;   // 20000
    int E = in_sizes[1] / 2;    // 640000
    float* out = (float*)d_out;

    char* p = (char*)d_ws;
    auto alloc = [&](size_t bytes) { char* r = p; p += (bytes + 255) & ~255ULL; return r; };
    float* dinv  = (float*)alloc((size_t)N * 4);
    int*   cnt   = (int*)alloc((size_t)N * 4);
    int*   cursor= (int*)alloc((size_t)N * 4);
    int*   boff  = (int*)alloc((NB + 1) * 4);
    double* part = (double*)alloc((size_t)PSLICE * NB * NFEAT * 4 * 8);
    unsigned int* pairs = (unsigned int*)alloc((size_t)N * CAP * 4);
    float* S1    = (float*)alloc((size_t)N * 256 * 4);
    float* S2    = (float*)alloc((size_t)N * 384 * 4);
    unsigned short* S1h = (unsigned short*)alloc((size_t)3 * N * 64 * 2);
    unsigned short* xh  = (unsigned short*)alloc((size_t)N * 64 * 2);
    float* b1A   = (float*)alloc((size_t)N * 64 * 4);
    float* b1B   = (float*)alloc((size_t)N * 64 * 4);
    unsigned short* h1A = (unsigned short*)alloc((size_t)N * 64 * 2);
    unsigned short* h1B = (unsigned short*)alloc((size_t)N * 64 * 2);
    float* prev1 = (float*)alloc((size_t)N * 64 * 4);
    float* b2A   = (float*)alloc((size_t)3 * N * 64 * 4);
    float* b2B   = (float*)alloc((size_t)3 * N * 64 * 4);
    unsigned short* h2A = (unsigned short*)alloc((size_t)3 * N * 64 * 2);
    unsigned short* h2B = (unsigned short*)alloc((size_t)3 * N * 64 * 2);
    float* prev2 = (float*)alloc((size_t)3 * N * 64 * 4);

    hipMemsetAsync(cnt, 0, (size_t)N * 4, stream);
    hipMemsetAsync(cursor, 0, (size_t)N * 4, stream);

    count_edges<<<(E + 255) / 256, 256, 0, stream>>>(ei, E, cnt);
    compute_dinv<<<(N + 255) / 256, 256, 0, stream>>>(cnt, dinv, N);
    fill_edges<<<(E + 255) / 256, 256, 0, stream>>>(ei, E, dinv, cursor, pairs);
    pad_edges<<<(N + 255) / 256, 256, 0, stream>>>(cnt, pairs, N);
    batch_bounds<<<(N + 255) / 256, 256, 0, stream>>>(batch, N, boff);
    convert_f16<<<(N * 64 + 255) / 256, 256, 0, stream>>>(x, xh, N * 64);

    long nu = (long)N * 64;
    int cgrid = (N + 3) / 4;

    // ---- phase A: L1 steps 1..8 (snap s=1; diffs s=2,4,8 -> S1 slots 0..2 + S1h) ----
    for (int s = 1; s <= 8; ++s) {
        const float* si = (s == 1) ? x  : ((s & 1) ? b1B : b1A);
        const unsigned short* mi = (s == 1) ? xh : ((s & 1) ? h1B : h1A);
        float* so = (s & 1) ? b1A : b1B;
        unsigned short* mo = (s & 1) ? h1A : h1B;
        cascade_k<1, 0><<<cgrid, 256, 0, stream>>>(
            si, mi, so, mo, prev1, s,
            nullptr, 0, 0, nullptr, 0, nullptr, nullptr, nullptr, 0,
            pairs, cnt, dinv, N, S1, S1h, S2);
    }

    // ---- phase B: fused — L1 step t=f+8 with L2 step f, f=1..8 ----
    for (int f = 1; f <= 8; ++f) {
        int t = f + 8;
        const float* s1i = ((t - 1) & 1) ? b1A : b1B;
        const unsigned short* m1i = ((t - 1) & 1) ? h1A : h1B;
        float* s1o = (t & 1) ? b1A : b1B;
        unsigned short* m1o = (t & 1) ? h1A : h1B;
        const float* s2i; int sstride2; long usz2;
        const unsigned short* m2i; long musz2;
        if (f == 1) { s2i = S1; sstride2 = 256; usz2 = 64; m2i = S1h; musz2 = nu; }
        else {
            s2i = ((f - 1) & 1) ? b2A : b2B; sstride2 = 64; usz2 = nu;
            m2i = ((f - 1) & 1) ? h2A : h2B; musz2 = nu;
        }
        float* s2o = (f & 1) ? b2A : b2B;
        unsigned short* m2o = (f & 1) ? h2A : h2B;
        cascade_k<1, 3><<<cgrid, 256, 0, stream>>>(
            s1i, m1i, s1o, m1o, prev1, t,
            s2i, sstride2, usz2, m2i, musz2, s2o, m2o, prev2, f,
            pairs, cnt, dinv, N, S1, S1h, S2);
    }

    // ---- phase C: L2-only steps 9..16 (diffs at 16 -> S2 slots 3,4,5) ----
    for (int s = 9; s <= 16; ++s) {
        const float* s2i = ((s - 1) & 1) ? b2A : b2B;
        const unsigned short* m2i = ((s - 1) & 1) ? h2A : h2B;
        float* s2o = (s & 1) ? b2A : b2B;
        unsigned short* m2o = (s & 1) ? h2A : h2B;
        cascade_k<0, 3><<<cgrid, 256, 0, stream>>>(
            nullptr, nullptr, nullptr, nullptr, nullptr, 0,
            s2i, 64, nu, m2i, nu, s2o, m2o, prev2, s,
            pairs, cnt, dinv, N, S1, S1h, S2);
    }

    moments_part<<<NB * 11 * MSLICE, 256, 0, stream>>>(x, S1, S2, boff, part);

    int fin_threads = NB * NFEAT + 68;
    finalize_k<<<(fin_threads + 255) / 256, 256, 0, stream>>>(part, boff, W, out);
}